// Round 1
// baseline (217.000 us; speedup 1.0000x reference)
//
#include <hip/hip_runtime.h>
#include <math.h>

// InfoNCE with exact JAX threefry2x32 negative-sampling reproduction.
// I=4096 items, E=16384 entities, D=64. Key insight: only ~66 sim values
// per row are ever needed; the mandatory work is reading adj (256MB) and
// reproducing jax.random.uniform(key(42), (I,E)) bit-exactly.

constexpr int D        = 64;
constexpr int EMAX     = 16384;
constexpr int POS_CAP  = 256;   // num_pos ~ Binom(16384, .002): mean 33, max ~62
constexpr int CAND_CAP = 384;   // bin population ~ Binom(16384, 1/256): mean 64
constexpr int SEL_CAP  = 256;   // k <= num_pos <= POS_CAP

// JAX threefry2x32, key = (0, 42) from jax.random.key(42).
__device__ __forceinline__ void threefry2x32(unsigned x0, unsigned x1,
                                             unsigned& o0, unsigned& o1) {
  const unsigned ks0 = 0u;
  const unsigned ks1 = 42u;
  const unsigned ks2 = 0x1BD11BDAu ^ 0u ^ 42u;
  x0 += ks0; x1 += ks1;
#define TF_R(r) { x0 += x1; x1 = (x1 << (r)) | (x1 >> (32 - (r))); x1 ^= x0; }
  TF_R(13) TF_R(15) TF_R(26) TF_R(6)
  x0 += ks1; x1 += ks2 + 1u;
  TF_R(17) TF_R(29) TF_R(16) TF_R(24)
  x0 += ks2; x1 += ks0 + 2u;
  TF_R(13) TF_R(15) TF_R(26) TF_R(6)
  x0 += ks0; x1 += ks1 + 3u;
  TF_R(17) TF_R(29) TF_R(16) TF_R(24)
  x0 += ks1; x1 += ks2 + 4u;
  TF_R(13) TF_R(15) TF_R(26) TF_R(6)
  x0 += ks2; x1 += ks0 + 5u;
#undef TF_R
  o0 = x0; o1 = x1;
}

// cosine sim / T for entity e against pre-scaled item row in LDS
// (itemn[d] = item[d] * rnorm_item / T); entity norm computed in-pass.
__device__ __forceinline__ float dot_sim(const float* __restrict__ ent, int e,
                                         const float* itemn) {
  const float4* er = (const float4*)(ent + ((size_t)e << 6));
  float dot = 0.f, ss = 0.f;
#pragma unroll
  for (int q = 0; q < 16; ++q) {
    float4 f = er[q];
    dot += itemn[4 * q + 0] * f.x + itemn[4 * q + 1] * f.y +
           itemn[4 * q + 2] * f.z + itemn[4 * q + 3] * f.w;
    ss += f.x * f.x + f.y * f.y + f.z * f.z + f.w * f.w;
  }
  return dot * (1.0f / sqrtf(ss));
}

__device__ __forceinline__ float block_max(float v, float* wred, int t) {
#pragma unroll
  for (int off = 32; off; off >>= 1) v = fmaxf(v, __shfl_xor(v, off, 64));
  __syncthreads();  // protect wred reuse
  if ((t & 63) == 0) wred[t >> 6] = v;
  __syncthreads();
  return fmaxf(fmaxf(wred[0], wred[1]), fmaxf(wred[2], wred[3]));
}

__device__ __forceinline__ float block_sum(float v, float* wred, int t) {
#pragma unroll
  for (int off = 32; off; off >>= 1) v += __shfl_xor(v, off, 64);
  __syncthreads();
  if ((t & 63) == 0) wred[t >> 6] = v;
  __syncthreads();
  return wred[0] + wred[1] + wred[2] + wred[3];
}

// One block handles row pair (iA, iA + I/2): they share threefry counter
// pairs (jA, jA + 2^25) -> (out0 -> row A, out1 -> row B).
__global__ __launch_bounds__(256) void infonce_main(
    const float* __restrict__ item, const float* __restrict__ ent,
    const int* __restrict__ adj, int I, int E,
    float* __restrict__ accum, int* __restrict__ paircnt) {
  const int t = threadIdx.x;
  const int halfI = I >> 1;
  const int iA = blockIdx.x;
  const int iB = iA + halfI;
  const unsigned HALF = (unsigned)halfI * (unsigned)E;  // 2^25

  __shared__ unsigned char s_u8[2][EMAX];  // top-8 bits of u23; 0xFF = positive
  __shared__ int s_pos[2][POS_CAP];
  __shared__ int s_hist[256];
  __shared__ unsigned s_ckey[CAND_CAP];
  __shared__ int s_cidx[CAND_CAP];
  __shared__ int s_sel[SEL_CAP];
  __shared__ float s_sim[SEL_CAP];
  __shared__ float s_itemn[D];
  __shared__ float s_wred[4];
  __shared__ int s_np[2];
  __shared__ int s_ncand, s_nsel, s_bbin, s_cbef;
  __shared__ float s_scale;

  if (t < 2) s_np[t] = 0;
  __syncthreads();

  // ---- Phase 1: stream both adj rows, one threefry per element pair ----
  const int nvec = E >> 2;
  const int4* adjA = (const int4*)(adj + (size_t)iA * E);
  const int4* adjB = (const int4*)(adj + (size_t)iB * E);
  unsigned* u32A = (unsigned*)s_u8[0];
  unsigned* u32B = (unsigned*)s_u8[1];
  const unsigned baseA = (unsigned)iA * (unsigned)E;
  for (int v = t; v < nvec; v += 256) {
    int4 a4 = adjA[v];
    int4 b4 = adjB[v];
    int av[4] = {a4.x, a4.y, a4.z, a4.w};
    int bv[4] = {b4.x, b4.y, b4.z, b4.w};
    unsigned e0 = (unsigned)v * 4u;
    unsigned wa = 0u, wb = 0u;
#pragma unroll
    for (int c = 0; c < 4; ++c) {
      unsigned o0, o1;
      threefry2x32(baseA + e0 + c, baseA + e0 + c + HALF, o0, o1);
      // u23 = bits >> 9 (uniform key); store top 8 bits = bits >> 24
      unsigned ua = (av[c] > 0) ? 0xFFu : (o0 >> 24);
      unsigned ub = (bv[c] > 0) ? 0xFFu : (o1 >> 24);
      wa |= ua << (8 * c);
      wb |= ub << (8 * c);
      if (av[c] > 0) { int s = atomicAdd(&s_np[0], 1); if (s < POS_CAP) s_pos[0][s] = (int)(e0 + c); }
      if (bv[c] > 0) { int s = atomicAdd(&s_np[1], 1); if (s < POS_CAP) s_pos[1][s] = (int)(e0 + c); }
    }
    u32A[v] = wa;
    u32B[v] = wb;
  }
  __syncthreads();

  // ---- Phase 2: per-row selection + loss ----
  for (int r2 = 0; r2 < 2; ++r2) {
    const int row = r2 ? iB : iA;
    const int npos = min(s_np[r2], POS_CAP);
    const int k = min(npos, E - npos);  // NEG_RATIO = 1.0
    if (npos > 0 && k > 0) {            // block-uniform branch
      s_hist[t] = 0;
      if (t == 0) { s_ncand = 0; s_nsel = 0; }
      __syncthreads();

      const unsigned* u32r = r2 ? u32B : u32A;
      for (int v = t; v < nvec; v += 256) {
        unsigned w = u32r[v];
#pragma unroll
        for (int c = 0; c < 4; ++c) {
          unsigned b8 = (w >> (8 * c)) & 0xFFu;
          if (b8 != 0xFFu) atomicAdd(&s_hist[b8], 1);
        }
      }
      __syncthreads();

      if (t == 0) {  // expected threshold bin b ~ 0; tiny serial scan
        int cum = 0, b = 0;
        while (b < 254 && cum + s_hist[b] < k) { cum += s_hist[b]; ++b; }
        s_bbin = b; s_cbef = cum;
      }
      __syncthreads();
      const int b = s_bbin;
      const int cbef = s_cbef;

      // bins < b are definitely selected; bin == b -> exact-rank candidates
      for (int v = t; v < nvec; v += 256) {
        unsigned w = u32r[v];
#pragma unroll
        for (int c = 0; c < 4; ++c) {
          int b8 = (int)((w >> (8 * c)) & 0xFFu);
          if (b8 < b) {
            int s = atomicAdd(&s_nsel, 1);
            if (s < SEL_CAP) s_sel[s] = v * 4 + c;
          } else if (b8 == b && b8 != 0xFF) {
            int s = atomicAdd(&s_ncand, 1);
            if (s < CAND_CAP) s_cidx[s] = v * 4 + c;
          }
        }
      }
      __syncthreads();
      const int ncand = min(s_ncand, CAND_CAP);

      if (t < ncand) {  // recompute full 23-bit keys for candidates only
        int e = s_cidx[t];
        unsigned o0, o1;
        threefry2x32(baseA + (unsigned)e, baseA + (unsigned)e + HALF, o0, o1);
        s_ckey[t] = (r2 ? o1 : o0) >> 9;
      }
      __syncthreads();
      const int rneed = k - cbef;
      if (t < ncand) {  // O(n^2) exact rank with stable-sort tie-break (key, idx)
        unsigned mykey = s_ckey[t];
        int myidx = s_cidx[t];
        int rank = 0;
        for (int c = 0; c < ncand; ++c) {
          unsigned ck = s_ckey[c];
          int ci = s_cidx[c];
          rank += (ck < mykey || (ck == mykey && ci < myidx)) ? 1 : 0;
        }
        if (rank < rneed) {
          int s = atomicAdd(&s_nsel, 1);
          if (s < SEL_CAP) s_sel[s] = myidx;
        }
      }

      // item row: scale = 1/||item|| / T folded into LDS copy
      float iv = 0.f;
      if (t < D) iv = item[(size_t)row * D + t];
      if (t < 64) {
        float ss = iv * iv;
#pragma unroll
        for (int off = 32; off; off >>= 1) ss += __shfl_xor(ss, off, 64);
        if (t == 0) s_scale = (1.0f / sqrtf(ss)) * (1.0f / 0.07f);
      }
      __syncthreads();  // also orders the rank-append pass above
      if (t < D) s_itemn[t] = iv * s_scale;
      __syncthreads();
      const int nsel = min(s_nsel, SEL_CAP);  // == k

      if (t < nsel) s_sim[t] = dot_sim(ent, s_sel[t], s_itemn);
      float v1 = (t < nsel) ? s_sim[t] : -INFINITY;
      const float m = block_max(v1, s_wred, t);
      float v2 = (t < nsel) ? expf(s_sim[t] - m) : 0.f;
      const float S = block_sum(v2, s_wred, t);

      float lp = 0.f;
      if (t < npos) {
        float sp = dot_sim(ent, s_pos[r2][t], s_itemn);
        float pm = fmaxf(sp, m);
        lp = logf(expf(sp - pm) + S * expf(m - pm)) + pm - sp;
      }
      const float rowloss = block_sum(lp, s_wred, t);
      if (t == 0) {
        atomicAdd(accum, rowloss);
        atomicAdd(paircnt, npos);
      }
      __syncthreads();
    }
  }
}

__global__ void infonce_init(float* accum, int* cnt) {
  if (threadIdx.x == 0 && blockIdx.x == 0) { accum[0] = 0.f; cnt[0] = 0; }
}

__global__ void infonce_final(const float* __restrict__ accum,
                              const int* __restrict__ cnt,
                              float* __restrict__ out) {
  if (threadIdx.x == 0 && blockIdx.x == 0) {
    int n = cnt[0];
    out[0] = (n > 0) ? accum[0] / (float)n : 0.f;
  }
}

extern "C" void kernel_launch(void* const* d_in, const int* in_sizes, int n_in,
                              void* d_out, int out_size, void* d_ws, size_t ws_size,
                              hipStream_t stream) {
  const float* item = (const float*)d_in[0];
  const float* ent  = (const float*)d_in[1];
  const int*   adj  = (const int*)d_in[2];
  const int I = in_sizes[0] / D;   // 4096
  const int E = in_sizes[1] / D;   // 16384

  float* accum = (float*)d_ws;       // 4 B
  int*   cnt   = ((int*)d_ws) + 1;   // 4 B

  infonce_init<<<1, 64, 0, stream>>>(accum, cnt);
  infonce_main<<<I / 2, 256, 0, stream>>>(item, ent, adj, I, E, accum, cnt);
  infonce_final<<<1, 64, 0, stream>>>(accum, cnt, (float*)d_out);
}

// Round 2
// 188.098 us; speedup vs baseline: 1.1537x; 1.1537x over previous
//
#include <hip/hip_runtime.h>
#include <math.h>

// InfoNCE with exact JAX threefry2x32 negative-sampling reproduction.
// I=4096 items, E=16384 entities, D=64. Mandatory work: read adj (256MB),
// one threefry per element PAIR (rows i and i+2048 share an eval), select
// k smallest uniforms per row among negatives, ~66 dot products per row.
//
// R1 change: selection fused into the threefry pass. The k-th smallest key
// is almost surely in top-8-bit bin 0 (bin-0 count ~64 >> k~33), so we
// collect bin-0 candidates + full keys during phase 1 and just rank them.
// Rare fallback (bin0 < k) rescans that one row. LDS 41KB -> 12KB.

constexpr int D        = 64;
constexpr int POS_CAP  = 256;   // num_pos ~ Binom(16384,.002): mean 33, max ~62
constexpr int CAND_CAP = 384;   // bin-0 count ~ Binom(16384,1/256): mean 64
constexpr int SEL_CAP  = 256;   // k <= num_pos

// JAX threefry2x32, key = (0, 42) from jax.random.key(42).
__device__ __forceinline__ void threefry2x32(unsigned x0, unsigned x1,
                                             unsigned& o0, unsigned& o1) {
  const unsigned ks0 = 0u;
  const unsigned ks1 = 42u;
  const unsigned ks2 = 0x1BD11BDAu ^ 0u ^ 42u;
  x0 += ks0; x1 += ks1;
#define TF_R(r) { x0 += x1; x1 = (x1 << (r)) | (x1 >> (32 - (r))); x1 ^= x0; }
  TF_R(13) TF_R(15) TF_R(26) TF_R(6)
  x0 += ks1; x1 += ks2 + 1u;
  TF_R(17) TF_R(29) TF_R(16) TF_R(24)
  x0 += ks2; x1 += ks0 + 2u;
  TF_R(13) TF_R(15) TF_R(26) TF_R(6)
  x0 += ks0; x1 += ks1 + 3u;
  TF_R(17) TF_R(29) TF_R(16) TF_R(24)
  x0 += ks1; x1 += ks2 + 4u;
  TF_R(13) TF_R(15) TF_R(26) TF_R(6)
  x0 += ks2; x1 += ks0 + 5u;
#undef TF_R
  o0 = x0; o1 = x1;
}

// cosine sim / T for entity e against pre-scaled item row in LDS
// (itemn[d] = item[d] / ||item|| / T); entity norm computed in-pass.
__device__ __forceinline__ float dot_sim(const float* __restrict__ ent, int e,
                                         const float* itemn) {
  const float4* er = (const float4*)(ent + ((size_t)e << 6));
  float dot = 0.f, ss = 0.f;
#pragma unroll
  for (int q = 0; q < 16; ++q) {
    float4 f = er[q];
    dot += itemn[4 * q + 0] * f.x + itemn[4 * q + 1] * f.y +
           itemn[4 * q + 2] * f.z + itemn[4 * q + 3] * f.w;
    ss += f.x * f.x + f.y * f.y + f.z * f.z + f.w * f.w;
  }
  return dot * (1.0f / sqrtf(ss));
}

__device__ __forceinline__ float block_max(float v, float* wred, int t) {
#pragma unroll
  for (int off = 32; off; off >>= 1) v = fmaxf(v, __shfl_xor(v, off, 64));
  __syncthreads();  // protect wred reuse
  if ((t & 63) == 0) wred[t >> 6] = v;
  __syncthreads();
  return fmaxf(fmaxf(wred[0], wred[1]), fmaxf(wred[2], wred[3]));
}

__device__ __forceinline__ float block_sum(float v, float* wred, int t) {
#pragma unroll
  for (int off = 32; off; off >>= 1) v += __shfl_xor(v, off, 64);
  __syncthreads();
  if ((t & 63) == 0) wred[t >> 6] = v;
  __syncthreads();
  return wred[0] + wred[1] + wred[2] + wred[3];
}

// One block handles row pair (iA, iA + I/2): element j of row iA is out0 of
// threefry(j_glob, j_glob + 2^25); element j of row iB is out1 of the SAME eval.
__global__ __launch_bounds__(256) void infonce_main(
    const float* __restrict__ item, const float* __restrict__ ent,
    const int* __restrict__ adj, int I, int E,
    double* __restrict__ accum, int* __restrict__ paircnt) {
  const int t = threadIdx.x;
  const int halfI = I >> 1;
  const int iA = blockIdx.x;
  const int iB = iA + halfI;
  const unsigned HALF = (unsigned)halfI * (unsigned)E;  // 2^25
  const unsigned baseA = (unsigned)iA * (unsigned)E;

  __shared__ int s_pos[2][POS_CAP];
  __shared__ int s_cidx[2][CAND_CAP];
  __shared__ unsigned s_ckey[2][CAND_CAP];
  __shared__ int s_sel[SEL_CAP];
  __shared__ int s_hist[256];          // fallback only
  __shared__ float s_itemn[D];
  __shared__ float s_wred[4];
  __shared__ int s_np[2], s_nc[2];
  __shared__ int s_nsel, s_bbin, s_cbef, s_fnc;
  __shared__ float s_scale;

  if (t < 2) { s_np[t] = 0; s_nc[t] = 0; }
  __syncthreads();

  // ---- Phase 1: stream both adj rows; one threefry per element pair;
  //      collect positives and bin-0 candidates (with full 23-bit keys) ----
  const int nvec = E >> 2;
  const int4* adjA = (const int4*)(adj + (size_t)iA * E);
  const int4* adjB = (const int4*)(adj + (size_t)iB * E);
  for (int v = t; v < nvec; v += 256) {
    int4 a4 = adjA[v];
    int4 b4 = adjB[v];
    int av[4] = {a4.x, a4.y, a4.z, a4.w};
    int bv[4] = {b4.x, b4.y, b4.z, b4.w};
    unsigned e0 = (unsigned)v * 4u;
#pragma unroll
    for (int c = 0; c < 4; ++c) {
      unsigned o0, o1;
      threefry2x32(baseA + e0 + c, baseA + e0 + c + HALF, o0, o1);
      const int e = (int)(e0 + c);
      if (av[c] > 0) {
        int s = atomicAdd(&s_np[0], 1); if (s < POS_CAP) s_pos[0][s] = e;
      } else if ((o0 >> 24) == 0u) {
        int s = atomicAdd(&s_nc[0], 1);
        if (s < CAND_CAP) { s_cidx[0][s] = e; s_ckey[0][s] = o0 >> 9; }
      }
      if (bv[c] > 0) {
        int s = atomicAdd(&s_np[1], 1); if (s < POS_CAP) s_pos[1][s] = e;
      } else if ((o1 >> 24) == 0u) {
        int s = atomicAdd(&s_nc[1], 1);
        if (s < CAND_CAP) { s_cidx[1][s] = e; s_ckey[1][s] = o1 >> 9; }
      }
    }
  }
  __syncthreads();

  // ---- Phase 2: per-row rank + loss ----
  for (int r2 = 0; r2 < 2; ++r2) {
    const int row = r2 ? iB : iA;
    const int npos = min(s_np[r2], POS_CAP);
    const int k = min(npos, E - npos);  // NEG_RATIO = 1.0
    if (npos > 0 && k > 0) {            // block-uniform branch
      if (t == 0) s_nsel = 0;
      __syncthreads();

      int ncand = min(s_nc[r2], CAND_CAP);
      int rneed = k;
      if (ncand < k) {
        // ---- rare exact fallback (~1e-3 of rows): full histogram rescan ----
        s_hist[t] = 0;
        if (t == 0) s_fnc = 0;
        __syncthreads();
        const int* adjR = adj + (size_t)row * E;
        for (int e = t; e < E; e += 256) {
          if (adjR[e] > 0) continue;
          unsigned o0, o1;
          threefry2x32(baseA + (unsigned)e, baseA + (unsigned)e + HALF, o0, o1);
          atomicAdd(&s_hist[(r2 ? o1 : o0) >> 24], 1);
        }
        __syncthreads();
        if (t == 0) {
          int cum = 0, b = 0;
          while (b < 255 && cum + s_hist[b] < k) { cum += s_hist[b]; ++b; }
          s_bbin = b; s_cbef = cum;
        }
        __syncthreads();
        const int b = s_bbin;
        for (int e = t; e < E; e += 256) {
          if (adjR[e] > 0) continue;
          unsigned o0, o1;
          threefry2x32(baseA + (unsigned)e, baseA + (unsigned)e + HALF, o0, o1);
          unsigned bits = r2 ? o1 : o0;
          int b8 = (int)(bits >> 24);
          if (b8 < b) {
            int s = atomicAdd(&s_nsel, 1); if (s < SEL_CAP) s_sel[s] = e;
          } else if (b8 == b) {
            int s = atomicAdd(&s_fnc, 1);
            if (s < CAND_CAP) { s_cidx[r2][s] = e; s_ckey[r2][s] = bits >> 9; }
          }
        }
        __syncthreads();
        ncand = min(s_fnc, CAND_CAP);
        rneed = k - s_cbef;
      }

      // exact rank among candidates, stable-sort tie-break (key, idx)
      for (int c0 = t; c0 < ncand; c0 += 256) {
        unsigned mykey = s_ckey[r2][c0];
        int myidx = s_cidx[r2][c0];
        int rank = 0;
        for (int c = 0; c < ncand; ++c) {
          unsigned ck = s_ckey[r2][c];
          int ci = s_cidx[r2][c];
          rank += (ck < mykey || (ck == mykey && ci < myidx)) ? 1 : 0;
        }
        if (rank < rneed) {
          int s = atomicAdd(&s_nsel, 1); if (s < SEL_CAP) s_sel[s] = myidx;
        }
      }

      // item row: scale = 1/||item|| / T folded into LDS copy
      float iv = 0.f;
      if (t < D) iv = item[(size_t)row * D + t];
      if (t < 64) {
        float ss = iv * iv;
#pragma unroll
        for (int off = 32; off; off >>= 1) ss += __shfl_xor(ss, off, 64);
        if (t == 0) s_scale = (1.0f / sqrtf(ss)) * (1.0f / 0.07f);
      }
      __syncthreads();  // also orders the rank-append pass above
      if (t < D) s_itemn[t] = iv * s_scale;
      __syncthreads();
      const int nsel = min(s_nsel, SEL_CAP);  // == k

      float myv = (t < nsel) ? dot_sim(ent, s_sel[t], s_itemn) : -INFINITY;
      const float m = block_max(myv, s_wred, t);
      float v2 = (t < nsel) ? expf(myv - m) : 0.f;
      const float S = block_sum(v2, s_wred, t);

      float lp = 0.f;
      if (t < npos) {
        float sp = dot_sim(ent, s_pos[r2][t], s_itemn);
        float pm = fmaxf(sp, m);
        lp = logf(expf(sp - pm) + S * expf(m - pm)) + pm - sp;
      }
      const float rowloss = block_sum(lp, s_wred, t);
      if (t == 0) {
        atomicAdd(accum, (double)rowloss);
        atomicAdd(paircnt, npos);
      }
      __syncthreads();
    }
  }
}

__global__ void infonce_init(double* accum, int* cnt) {
  if (threadIdx.x == 0 && blockIdx.x == 0) { accum[0] = 0.0; cnt[0] = 0; }
}

__global__ void infonce_final(const double* __restrict__ accum,
                              const int* __restrict__ cnt,
                              float* __restrict__ out) {
  if (threadIdx.x == 0 && blockIdx.x == 0) {
    int n = cnt[0];
    out[0] = (n > 0) ? (float)(accum[0] / (double)n) : 0.f;
  }
}

extern "C" void kernel_launch(void* const* d_in, const int* in_sizes, int n_in,
                              void* d_out, int out_size, void* d_ws, size_t ws_size,
                              hipStream_t stream) {
  const float* item = (const float*)d_in[0];
  const float* ent  = (const float*)d_in[1];
  const int*   adj  = (const int*)d_in[2];
  const int I = in_sizes[0] / D;   // 4096
  const int E = in_sizes[1] / D;   // 16384

  double* accum = (double*)d_ws;                 // 8 B
  int*    cnt   = (int*)((char*)d_ws + 8);       // 4 B

  infonce_init<<<1, 64, 0, stream>>>(accum, cnt);
  infonce_main<<<I / 2, 256, 0, stream>>>(item, ent, adj, I, E, accum, cnt);
  infonce_final<<<1, 64, 0, stream>>>(accum, cnt, (float*)d_out);
}